// Round 5
// baseline (237.566 us; speedup 1.0000x reference)
//
#include <hip/hip_runtime.h>
#include <math.h>

typedef unsigned short u16;
typedef unsigned int u32;
typedef __attribute__((ext_vector_type(8))) short short8;  // 8 bf16 (4 VGPR)
typedef __attribute__((ext_vector_type(4))) float f32x4;   // MFMA acc

#define DEVI __device__ __forceinline__

DEVI u16 f2bf(float x) {
    union { float f; u32 u; } un; un.f = x;
    u32 u = un.u;
    return (u16)((u + 0x7fffu + ((u >> 16) & 1u)) >> 16);  // RTNE
}
// HW packed convert, RTNE — bit-identical to f2bf, 2 converts in 1 op.
DEVI u32 cvtpk(float lo, float hi) {
    u32 r;
    asm("v_cvt_pk_bf16_f32 %0, %1, %2" : "=v"(r) : "v"(lo), "v"(hi));
    return r;
}
DEVI float bf2f(u16 v) {
    union { u32 u; float f; } un; un.u = ((u32)v) << 16;
    return un.f;
}
DEVI f32x4 mfma_bf16(short8 a, short8 b, f32x4 c) {
    return __builtin_amdgcn_mfma_f32_16x16x32_bf16(a, b, c, 0, 0, 0);
}
// async global->LDS, 16B/lane. LDS dest = wave-uniform base + lane*16.
DEVI void gload_lds16(const void* g, void* l) {
    __builtin_amdgcn_global_load_lds((const __attribute__((address_space(1))) u32*)g,
                                     (__attribute__((address_space(3))) u32*)l,
                                     16, 0, 0);
}

// ---------------- fused prep: x->bf16 convert + Wqkv^T + Wout^T ----------------
__global__ void k_prep(const float* __restrict__ x, const float* __restrict__ Wqkv,
                       const float* __restrict__ Wout, u16* __restrict__ x_bf,
                       u16* __restrict__ WqkvT, u16* __restrict__ WoutT) {
    __shared__ u16 tile[64][68];
    const int bid = blockIdx.x;
    if (bid < 4096) {
        long idx = ((long)bid * 256 + threadIdx.x) * 4;
        float4 v = *(const float4*)(x + idx);
        uint2 o;
        o.x = cvtpk(v.x, v.y);
        o.y = cvtpk(v.z, v.w);
        *(uint2*)(x_bf + idx) = o;
        return;
    }
    const float* in;
    u16* out;
    int R, C, bx, by;
    if (bid < 7168) {
        int lb = bid - 4096;
        in = Wqkv; out = WqkvT; R = 2048; C = 6144;
        bx = lb % 96; by = lb / 96;
    } else {
        int lb = bid - 7168;
        in = Wout; out = WoutT; R = 2048; C = 2048;
        bx = lb & 31; by = lb >> 5;
    }
    const int tx = threadIdx.x & 15, ty = threadIdx.x >> 4;
    const long r0 = (long)by * 64, c0 = (long)bx * 64;
#pragma unroll
    for (int p = 0; p < 4; ++p) {
        int r = ty + p * 16;
        float4 v = *(const float4*)(in + (r0 + r) * C + c0 + tx * 4);
        uint2 o;
        o.x = cvtpk(v.x, v.y);
        o.y = cvtpk(v.z, v.w);
        *(uint2*)&tile[r][tx * 4] = o;
    }
    __syncthreads();
#pragma unroll
    for (int p = 0; p < 4; ++p) {
        int rr = ty + p * 16;
        ushort4 o;
        o.x = tile[tx * 4 + 0][rr];
        o.y = tile[tx * 4 + 1][rr];
        o.z = tile[tx * 4 + 2][rr];
        o.w = tile[tx * 4 + 3][rr];
        *(ushort4*)(out + (c0 + rr) * R + r0 + tx * 4) = o;
    }
}

// ---------------- m97-style bf16 GEMM, XOR-swizzled LDS, templated tile-M ----------------
// C[bm*TM..+TM, bn*128..+128] = A[M,K] * BT[N,K]^T.
// T1 XCD swizzle: contiguous work chunk per XCD so B-panels become L2-resident
// (verified: FETCH 103 -> 48 MB). Grids are multiples of 8 -> bijective.
// EPI 0 (TM=128): QKV epilogue — RoPE q/k, v transposed into vT[32][128][1024].
// EPI 1 (TM=64):  +bias, fp32 store (smaller tile -> 512 blocks -> 2-3/CU).
template <int EPI, int TM>
__global__ __launch_bounds__(256, 3) void k_gemm(const u16* __restrict__ A,
                                                 const u16* __restrict__ BT, int K,
                                                 u16* __restrict__ qb, u16* __restrict__ kb,
                                                 u16* __restrict__ vtb, float* __restrict__ out,
                                                 const float* __restrict__ bias) {
    constexpr int MI = TM / 32;       // A-frags per wave (4 for TM=128, 2 for TM=64)
    constexpr int CA = TM / 32;       // A staging chunks per wave (nchA = TM/8, /4 waves)
    __shared__ __align__(16) union SM {
        struct { u16 As[TM * 64]; u16 Bs[128 * 64]; } s;   // swizzled staging
        u16 T[EPI == 0 ? 128 * 132 : 8];                   // epilogue tile (pad 132)
    } sm;
    const int tid = threadIdx.x;
    const int lane = tid & 63, wave = tid >> 6;
    const int lm = lane & 15, quad = lane >> 4;
    const int wm = wave >> 1, wn = wave & 1;
    // T1: XCD-aware block swizzle (dispatch id%8 ~ XCD; give each XCD a contiguous chunk)
    const int nwg = gridDim.x * gridDim.y;
    const int lin = blockIdx.y * gridDim.x + blockIdx.x;
    const int work = (lin & 7) * (nwg >> 3) + (lin >> 3);
    const int bm = work % gridDim.x, bn = work / gridDim.x;

    f32x4 acc[MI][4] = {};

    const int srow = lane >> 3;
    const int scb = (lane & 7) ^ srow;
    const long arow0 = (long)bm * TM;
    const long brow0 = (long)bn * 128;

    for (int k0 = 0; k0 < K; k0 += 64) {
        __syncthreads();
#pragma unroll
        for (int it = 0; it < CA; ++it) {
            int ch = wave * CA + it;
            long r = ch * 8 + srow;
            gload_lds16(A + (arow0 + r) * K + k0 + scb * 8, (char*)sm.s.As + ch * 1024);
        }
#pragma unroll
        for (int it = 0; it < 4; ++it) {
            int ch = wave * 4 + it;
            long r = ch * 8 + srow;
            gload_lds16(BT + (brow0 + r) * K + k0 + scb * 8, (char*)sm.s.Bs + ch * 1024);
        }
        __syncthreads();
#pragma unroll
        for (int ko = 0; ko < 2; ++ko) {
            short8 af[MI], bf[4];
#pragma unroll
            for (int i = 0; i < MI; ++i) {
                int row = wm * (TM / 2) + i * 16 + lm;
                int pc = (ko * 4 + quad) ^ (lm & 7);
                af[i] = *(const short8*)&sm.s.As[row * 64 + pc * 8];
            }
#pragma unroll
            for (int j = 0; j < 4; ++j) {
                int row = wn * 64 + j * 16 + lm;
                int pc = (ko * 4 + quad) ^ (lm & 7);
                bf[j] = *(const short8*)&sm.s.Bs[row * 64 + pc * 8];
            }
#pragma unroll
            for (int i = 0; i < MI; ++i)
#pragma unroll
                for (int j = 0; j < 4; ++j)
                    acc[i][j] = mfma_bf16(af[i], bf[j], acc[i][j]);
        }
    }

    if constexpr (EPI == 0) {
        __syncthreads();  // all waves done reading As/Bs
#pragma unroll
        for (int i = 0; i < MI; ++i)
#pragma unroll
            for (int j = 0; j < 4; ++j) {
                const int col = wn * 64 + j * 16 + lm;
                const int row0 = wm * 64 + i * 16 + quad * 4;
                const u32 p01 = cvtpk(acc[i][j][0], acc[i][j][1]);
                const u32 p23 = cvtpk(acc[i][j][2], acc[i][j][3]);
                sm.T[(row0 + 0) * 132 + col] = (u16)p01;
                sm.T[(row0 + 1) * 132 + col] = (u16)(p01 >> 16);
                sm.T[(row0 + 2) * 132 + col] = (u16)p23;
                sm.T[(row0 + 3) * 132 + col] = (u16)(p23 >> 16);
            }
        __syncthreads();
        const int which = bn >> 4, h = bn & 15, b = bm >> 3;
        const int p0 = (bm & 7) * 128;
        if (which < 2) {
            // RoPE + store to q/k buffer [bh][pos][128]
            u16* dst = which ? kb : qb;
            const long hb = ((long)(b * 16 + h)) * 1024;
            const int i0 = (tid * 4) & 63;   // c-invariant
            const int pb = tid >> 4;         // pos_l = c*16 + pb
            float inv[4];
#pragma unroll
            for (int e = 0; e < 4; ++e)
                inv[e] = exp2f(-(float)(i0 + e) * 0.20762050593045952f);  // log2(1e4)/64
#pragma unroll
            for (int c = 0; c < 8; ++c) {
                const int pos_l = c * 16 + pb;
                ushort4 cur = *(const ushort4*)&sm.T[pos_l * 132 + i0];
                ushort4 par = *(const ushort4*)&sm.T[pos_l * 132 + i0 + 64];
                const float pg = (float)(p0 + pos_l);
                const u16* cp = (const u16*)&cur;
                const u16* pp = (const u16*)&par;
                float f1[4], f2[4];
#pragma unroll
                for (int e = 0; e < 4; ++e) {
                    float th = pg * inv[e];
                    float sv = __sinf(th), cv = __cosf(th);  // v_sin/v_cos, |th|<=1023
                    float x1 = bf2f(cp[e]), x2 = bf2f(pp[e]);
                    f1[e] = x1 * cv - x2 * sv;
                    f2[e] = x2 * cv + x1 * sv;
                }
                uint2 o1, o2;
                o1.x = cvtpk(f1[0], f1[1]); o1.y = cvtpk(f1[2], f1[3]);
                o2.x = cvtpk(f2[0], f2[1]); o2.y = cvtpk(f2[2], f2[3]);
                const long rowb = (hb + p0 + pos_l) * 128;
                *(uint2*)(dst + rowb + i0) = o1;
                *(uint2*)(dst + rowb + i0 + 64) = o2;
            }
        } else {
            // V: store transposed into vT[32][128][1024]
            const long vrow = ((long)(b * 16 + h)) * 128;
#pragma unroll
            for (int c = 0; c < 8; ++c) {
                const int lin2 = c * 2048 + tid * 8;
                const int dk = lin2 >> 7;
                const int ps = lin2 & 127;
                ushort4 o1, o2;
                u16* o1p = (u16*)&o1;
                u16* o2p = (u16*)&o2;
#pragma unroll
                for (int e = 0; e < 4; ++e) {
                    o1p[e] = sm.T[(ps + e) * 132 + dk];
                    o2p[e] = sm.T[(ps + 4 + e) * 132 + dk];
                }
                u16* dst = vtb + (vrow + dk) * 1024 + p0 + ps;
                *(ushort4*)dst = o1;
                *(ushort4*)(dst + 4) = o2;
            }
        }
    } else {
        float bv[4];
#pragma unroll
        for (int j = 0; j < 4; ++j) bv[j] = bias[bn * 128 + wn * 64 + j * 16 + lm];
#pragma unroll
        for (int i = 0; i < MI; ++i) {
#pragma unroll
            for (int r = 0; r < 4; ++r) {
                const int row = bm * TM + wm * (TM / 2) + i * 16 + quad * 4 + r;
#pragma unroll
                for (int j = 0; j < 4; ++j) {
                    const int col = bn * 128 + wn * 64 + j * 16 + lm;
                    out[(long)row * 2048 + col] = acc[i][j][r] + bv[j];
                }
            }
        }
    }
}

// ---------------- flash attention (causal), S^T = K*Q^T, 2-phase dbuf prefetch ---------
// T1 XCD swizzle; T5 setprio; T13 defer-max.
// Diagonal K-tile split out of the bulk loop (mask cmp/cndmask only where needed);
// P-pack and output via v_cvt_pk_bf16_f32 (HW RTNE, bit-identical to f2bf).
__global__ __launch_bounds__(256, 2) void k_flash(const u16* __restrict__ Q,
                                                  const u16* __restrict__ Kb,
                                                  const u16* __restrict__ VT,
                                                  u16* __restrict__ R) {
    __shared__ u16 Ks[2][64 * 128];  // [key 64][d 128], swizzled mask 15
    __shared__ u16 Vs[2][128 * 64];  // [d 128][key 64], swizzled mask 7
    __shared__ u16 Ps[64 * 72];      // [q 64][key 64 + 8 pad]
    const int tid = threadIdx.x;
    const int lane = tid & 63, wave = tid >> 6;
    const int lm = lane & 15, quad = lane >> 4;
    const int id = (blockIdx.x & 7) * 64 + (blockIdx.x >> 3);  // T1 swizzle (512 blocks)
    const int g = id >> 8, rem = id & 255;
    const int bh = rem >> 3, s = rem & 7;
    const int qt = g ? (15 - s) : s;
    const long qkbase = (long)bh * 1024 * 128;
    const long vtbase = (long)bh * 128 * 1024;
    const int q0 = qt * 64;

    short8 qf[4];
    {
        const u16* qrow = Q + qkbase + (long)(q0 + wave * 16 + lm) * 128 + quad * 8;
#pragma unroll
        for (int kc = 0; kc < 4; ++kc) qf[kc] = *(const short8*)(qrow + kc * 32);
    }

    f32x4 o_acc[8] = {};
    float m_i = -INFINITY, l_i = 0.f;
    const float cl2e = 0.08838834764831845f * 1.4426950408889634f;  // 1/sqrt(128)*log2(e)

    const int kr = lane >> 4;
    const int vr = lane >> 3;
    const int vcb = (lane & 7) ^ vr;

    auto stage = [&](int buf, int kt) {
#pragma unroll
        for (int it = 0; it < 4; ++it) {
            int ch = wave * 4 + it;
            int krow = ch * 4 + kr;
            int kchunk = (lane & 15) ^ (krow & 15);
            gload_lds16(Kb + qkbase + (long)(kt * 64 + krow) * 128 + kchunk * 8,
                        (char*)Ks[buf] + ch * 1024);
            int vrow = ch * 8 + vr;
            gload_lds16(VT + vtbase + (long)vrow * 1024 + kt * 64 + vcb * 8,
                        (char*)Vs[buf] + ch * 1024);
        }
    };

    stage(0, 0);
    __syncthreads();  // implicit vmcnt(0): tile 0 ready
    int cur = 0;

    for (int kt = 0; kt <= qt; ++kt) {
        if (kt < qt) stage(cur ^ 1, kt + 1);  // issue prefetch, no wait
        asm volatile("" ::: "memory");        // keep issue before compute

        f32x4 s_acc[4] = {};
        __builtin_amdgcn_s_setprio(1);
#pragma unroll
        for (int kc = 0; kc < 4; ++kc) {
#pragma unroll
            for (int mi = 0; mi < 4; ++mi) {
                int row = mi * 16 + lm;
                int pc = (kc * 4 + quad) ^ lm;
                short8 ak = *(const short8*)&Ks[cur][row * 128 + pc * 8];
                s_acc[mi] = mfma_bf16(ak, qf[kc], s_acc[mi]);
            }
        }
        __builtin_amdgcn_s_setprio(0);
        float t[4][4];
        float cmax = -INFINITY;
        if (kt < qt) {
            // bulk tile: all keys valid (kg <= kt*64+63 < qt*64 <= qg), no mask ops
#pragma unroll
            for (int mi = 0; mi < 4; ++mi)
#pragma unroll
                for (int r = 0; r < 4; ++r) {
                    float val = s_acc[mi][r] * cl2e;
                    t[mi][r] = val;
                    cmax = fmaxf(cmax, val);
                }
        } else {
            const int qg = q0 + wave * 16 + lm;
#pragma unroll
            for (int mi = 0; mi < 4; ++mi)
#pragma unroll
                for (int r = 0; r < 4; ++r) {
                    int kg = kt * 64 + mi * 16 + quad * 4 + r;
                    float val = (kg <= qg) ? s_acc[mi][r] * cl2e : -INFINITY;
                    t[mi][r] = val;
                    cmax = fmaxf(cmax, val);
                }
        }
        cmax = fmaxf(cmax, __shfl_xor(cmax, 16));
        cmax = fmaxf(cmax, __shfl_xor(cmax, 32));
        // T13 defer-max: keep old max when per-row growth <= 8 (P bounded by 2^8)
        float m_new = fmaxf(m_i, cmax);
        const bool defer = __all(cmax - m_i <= 8.f);
        if (defer) m_new = m_i;
        float csum = 0.f;
#pragma unroll
        for (int mi = 0; mi < 4; ++mi)
#pragma unroll
            for (int r = 0; r < 4; ++r) {
                float p = exp2f(t[mi][r] - m_new);
                t[mi][r] = p;
                csum += p;
            }
        csum += __shfl_xor(csum, 16);
        csum += __shfl_xor(csum, 32);
        if (!defer) {
            float alpha = exp2f(m_i - m_new);
            float aq[4];
#pragma unroll
            for (int r = 0; r < 4; ++r) aq[r] = __shfl(alpha, quad * 4 + r, 64);
#pragma unroll
            for (int nt = 0; nt < 8; ++nt)
#pragma unroll
                for (int r = 0; r < 4; ++r) o_acc[nt][r] *= aq[r];
            l_i = l_i * alpha + csum;
        } else {
            l_i += csum;
        }
        m_i = m_new;
#pragma unroll
        for (int mi = 0; mi < 4; ++mi) {
            uint2 pk2;
            pk2.x = cvtpk(t[mi][0], t[mi][1]);
            pk2.y = cvtpk(t[mi][2], t[mi][3]);
            *(uint2*)&Ps[(wave * 16 + lm) * 72 + mi * 16 + quad * 4] = pk2;
        }
        __builtin_amdgcn_s_setprio(1);
#pragma unroll
        for (int kc = 0; kc < 2; ++kc) {
            short8 ap = *(const short8*)&Ps[(wave * 16 + lm) * 72 + kc * 32 + quad * 8];
#pragma unroll
            for (int nt = 0; nt < 8; ++nt) {
                int row = nt * 16 + lm;
                int pc = (kc * 4 + quad) ^ (lm & 7);
                short8 bv = *(const short8*)&Vs[cur][row * 64 + pc * 8];
                o_acc[nt] = mfma_bf16(ap, bv, o_acc[nt]);
            }
        }
        __builtin_amdgcn_s_setprio(0);
        __syncthreads();  // implicit vmcnt(0): prefetch landed; Ps WAR fence
        cur ^= 1;
    }
    float lq[4], il[4];
#pragma unroll
    for (int r = 0; r < 4; ++r) lq[r] = __shfl(l_i, quad * 4 + r, 64);
#pragma unroll
    for (int r = 0; r < 4; ++r) il[r] = 1.0f / lq[r];
    const int b = bh >> 4, h = bh & 15;
    const int pos0 = q0 + wave * 16 + quad * 4;
#pragma unroll
    for (int nt = 0; nt < 8; ++nt) {
        const int col = h * 128 + nt * 16 + lm;
        const u32 p01 = cvtpk(o_acc[nt][0] * il[0], o_acc[nt][1] * il[1]);
        const u32 p23 = cvtpk(o_acc[nt][2] * il[2], o_acc[nt][3] * il[3]);
        R[((long)b * 1024 + pos0 + 0) * 2048 + col] = (u16)p01;
        R[((long)b * 1024 + pos0 + 1) * 2048 + col] = (u16)(p01 >> 16);
        R[((long)b * 1024 + pos0 + 2) * 2048 + col] = (u16)p23;
        R[((long)b * 1024 + pos0 + 3) * 2048 + col] = (u16)(p23 >> 16);
    }
}

extern "C" void kernel_launch(void* const* d_in, const int* in_sizes, int n_in,
                              void* d_out, int out_size, void* d_ws, size_t ws_size,
                              hipStream_t stream) {
    const float* x    = (const float*)d_in[0];
    const float* Wqkv = (const float*)d_in[2];
    const float* Wout = (const float*)d_in[3];
    const float* bout = (const float*)d_in[4];
    float* out = (float*)d_out;

    char* ws = (char*)d_ws;
    u16* x_bf  = (u16*)(ws);                 // 8MB; dead after qkv GEMM
    u16* rbuf  = x_bf;                       // reuse: written by flash
    u16* WqkvT = (u16*)(ws + (8L << 20));    // 24MB
    u16* WoutT = (u16*)(ws + (32L << 20));   // 8MB
    u16* qbuf  = (u16*)(ws + (40L << 20));   // 8MB (roped)
    u16* kbuf  = (u16*)(ws + (48L << 20));   // 8MB (roped)
    u16* vtbuf = (u16*)(ws + (56L << 20));   // 8MB, vT[32][128][1024]

    k_prep<<<8192, 256, 0, stream>>>(x, Wqkv, Wout, x_bf, WqkvT, WoutT);
    k_gemm<0, 128><<<dim3(16, 48), 256, 0, stream>>>(x_bf, WqkvT, 2048, qbuf, kbuf, vtbuf,
                                                     nullptr, nullptr);
    k_flash<<<512, 256, 0, stream>>>(qbuf, kbuf, vtbuf, rbuf);
    k_gemm<1, 64><<<dim3(32, 16), 256, 0, stream>>>(rbuf, WoutT, 2048, nullptr, nullptr,
                                                    nullptr, out, bout);
}

// Round 6
// 235.202 us; speedup vs baseline: 1.0101x; 1.0101x over previous
//
#include <hip/hip_runtime.h>
#include <math.h>

typedef unsigned short u16;
typedef unsigned int u32;
typedef __attribute__((ext_vector_type(8))) short short8;  // 8 bf16 (4 VGPR)
typedef __attribute__((ext_vector_type(4))) float f32x4;   // MFMA acc

#define DEVI __device__ __forceinline__

DEVI u16 f2bf(float x) {
    union { float f; u32 u; } un; un.f = x;
    u32 u = un.u;
    return (u16)((u + 0x7fffu + ((u >> 16) & 1u)) >> 16);  // RTNE
}
// HW packed convert, RTNE — bit-identical to f2bf, 2 converts in 1 op.
DEVI u32 cvtpk(float lo, float hi) {
    u32 r;
    asm("v_cvt_pk_bf16_f32 %0, %1, %2" : "=v"(r) : "v"(lo), "v"(hi));
    return r;
}
DEVI float bf2f(u16 v) {
    union { u32 u; float f; } un; un.u = ((u32)v) << 16;
    return un.f;
}
DEVI f32x4 mfma_bf16(short8 a, short8 b, f32x4 c) {
    return __builtin_amdgcn_mfma_f32_16x16x32_bf16(a, b, c, 0, 0, 0);
}
// async global->LDS, 16B/lane. LDS dest = wave-uniform base + lane*16.
DEVI void gload_lds16(const void* g, void* l) {
    __builtin_amdgcn_global_load_lds((const __attribute__((address_space(1))) u32*)g,
                                     (__attribute__((address_space(3))) u32*)l,
                                     16, 0, 0);
}

// ---------------- fused prep: x->bf16 convert + Wqkv^T + Wout^T ----------------
__global__ void k_prep(const float* __restrict__ x, const float* __restrict__ Wqkv,
                       const float* __restrict__ Wout, u16* __restrict__ x_bf,
                       u16* __restrict__ WqkvT, u16* __restrict__ WoutT) {
    __shared__ u16 tile[64][68];
    const int bid = blockIdx.x;
    if (bid < 4096) {
        long idx = ((long)bid * 256 + threadIdx.x) * 4;
        float4 v = *(const float4*)(x + idx);
        uint2 o;
        o.x = cvtpk(v.x, v.y);
        o.y = cvtpk(v.z, v.w);
        *(uint2*)(x_bf + idx) = o;
        return;
    }
    const float* in;
    u16* out;
    int R, C, bx, by;
    if (bid < 7168) {
        int lb = bid - 4096;
        in = Wqkv; out = WqkvT; R = 2048; C = 6144;
        bx = lb % 96; by = lb / 96;
    } else {
        int lb = bid - 7168;
        in = Wout; out = WoutT; R = 2048; C = 2048;
        bx = lb & 31; by = lb >> 5;
    }
    const int tx = threadIdx.x & 15, ty = threadIdx.x >> 4;
    const long r0 = (long)by * 64, c0 = (long)bx * 64;
#pragma unroll
    for (int p = 0; p < 4; ++p) {
        int r = ty + p * 16;
        float4 v = *(const float4*)(in + (r0 + r) * C + c0 + tx * 4);
        uint2 o;
        o.x = cvtpk(v.x, v.y);
        o.y = cvtpk(v.z, v.w);
        *(uint2*)&tile[r][tx * 4] = o;
    }
    __syncthreads();
#pragma unroll
    for (int p = 0; p < 4; ++p) {
        int rr = ty + p * 16;
        ushort4 o;
        o.x = tile[tx * 4 + 0][rr];
        o.y = tile[tx * 4 + 1][rr];
        o.z = tile[tx * 4 + 2][rr];
        o.w = tile[tx * 4 + 3][rr];
        *(ushort4*)(out + (c0 + rr) * R + r0 + tx * 4) = o;
    }
}

// ---------------- m97-style bf16 GEMM, XOR-swizzled LDS, templated tile-M ----------------
// C[bm*TM..+TM, bn*128..+128] = A[M,K] * BT[N,K]^T.
// T1 XCD swizzle: contiguous work chunk per XCD so B-panels become L2-resident
// (verified: FETCH 103 -> 48 MB). Grids are multiples of 8 -> bijective.
// EPI 0 (TM=128): QKV epilogue — RoPE q/k, v transposed into vT[32][128][1024].
// EPI 1 (TM=64):  +bias, fp32 store (smaller tile -> 512 blocks -> 2-3/CU).
template <int EPI, int TM>
__global__ __launch_bounds__(256, 3) void k_gemm(const u16* __restrict__ A,
                                                 const u16* __restrict__ BT, int K,
                                                 u16* __restrict__ qb, u16* __restrict__ kb,
                                                 u16* __restrict__ vtb, float* __restrict__ out,
                                                 const float* __restrict__ bias) {
    constexpr int MI = TM / 32;       // A-frags per wave (4 for TM=128, 2 for TM=64)
    constexpr int CA = TM / 32;       // A staging chunks per wave (nchA = TM/8, /4 waves)
    __shared__ __align__(16) union SM {
        struct { u16 As[TM * 64]; u16 Bs[128 * 64]; } s;   // swizzled staging
        u16 T[EPI == 0 ? 128 * 132 : 8];                   // epilogue tile (pad 132)
    } sm;
    const int tid = threadIdx.x;
    const int lane = tid & 63, wave = tid >> 6;
    const int lm = lane & 15, quad = lane >> 4;
    const int wm = wave >> 1, wn = wave & 1;
    // T1: XCD-aware block swizzle (dispatch id%8 ~ XCD; give each XCD a contiguous chunk)
    const int nwg = gridDim.x * gridDim.y;
    const int lin = blockIdx.y * gridDim.x + blockIdx.x;
    const int work = (lin & 7) * (nwg >> 3) + (lin >> 3);
    const int bm = work % gridDim.x, bn = work / gridDim.x;

    f32x4 acc[MI][4] = {};

    const int srow = lane >> 3;
    const int scb = (lane & 7) ^ srow;
    const long arow0 = (long)bm * TM;
    const long brow0 = (long)bn * 128;

    for (int k0 = 0; k0 < K; k0 += 64) {
        __syncthreads();
#pragma unroll
        for (int it = 0; it < CA; ++it) {
            int ch = wave * CA + it;
            long r = ch * 8 + srow;
            gload_lds16(A + (arow0 + r) * K + k0 + scb * 8, (char*)sm.s.As + ch * 1024);
        }
#pragma unroll
        for (int it = 0; it < 4; ++it) {
            int ch = wave * 4 + it;
            long r = ch * 8 + srow;
            gload_lds16(BT + (brow0 + r) * K + k0 + scb * 8, (char*)sm.s.Bs + ch * 1024);
        }
        __syncthreads();
#pragma unroll
        for (int ko = 0; ko < 2; ++ko) {
            short8 af[MI], bf[4];
#pragma unroll
            for (int i = 0; i < MI; ++i) {
                int row = wm * (TM / 2) + i * 16 + lm;
                int pc = (ko * 4 + quad) ^ (lm & 7);
                af[i] = *(const short8*)&sm.s.As[row * 64 + pc * 8];
            }
#pragma unroll
            for (int j = 0; j < 4; ++j) {
                int row = wn * 64 + j * 16 + lm;
                int pc = (ko * 4 + quad) ^ (lm & 7);
                bf[j] = *(const short8*)&sm.s.Bs[row * 64 + pc * 8];
            }
#pragma unroll
            for (int i = 0; i < MI; ++i)
#pragma unroll
                for (int j = 0; j < 4; ++j)
                    acc[i][j] = mfma_bf16(af[i], bf[j], acc[i][j]);
        }
    }

    if constexpr (EPI == 0) {
        __syncthreads();  // all waves done reading As/Bs
#pragma unroll
        for (int i = 0; i < MI; ++i)
#pragma unroll
            for (int j = 0; j < 4; ++j) {
                const int col = wn * 64 + j * 16 + lm;
                const int row0 = wm * 64 + i * 16 + quad * 4;
                const u32 p01 = cvtpk(acc[i][j][0], acc[i][j][1]);
                const u32 p23 = cvtpk(acc[i][j][2], acc[i][j][3]);
                sm.T[(row0 + 0) * 132 + col] = (u16)p01;
                sm.T[(row0 + 1) * 132 + col] = (u16)(p01 >> 16);
                sm.T[(row0 + 2) * 132 + col] = (u16)p23;
                sm.T[(row0 + 3) * 132 + col] = (u16)(p23 >> 16);
            }
        __syncthreads();
        const int which = bn >> 4, h = bn & 15, b = bm >> 3;
        const int p0 = (bm & 7) * 128;
        if (which < 2) {
            // RoPE + store to q/k buffer [bh][pos][128]
            u16* dst = which ? kb : qb;
            const long hb = ((long)(b * 16 + h)) * 1024;
            const int i0 = (tid * 4) & 63;   // c-invariant
            const int pb = tid >> 4;         // pos_l = c*16 + pb
            float inv[4];
#pragma unroll
            for (int e = 0; e < 4; ++e)
                inv[e] = exp2f(-(float)(i0 + e) * 0.20762050593045952f);  // log2(1e4)/64
#pragma unroll
            for (int c = 0; c < 8; ++c) {
                const int pos_l = c * 16 + pb;
                ushort4 cur = *(const ushort4*)&sm.T[pos_l * 132 + i0];
                ushort4 par = *(const ushort4*)&sm.T[pos_l * 132 + i0 + 64];
                const float pg = (float)(p0 + pos_l);
                const u16* cp = (const u16*)&cur;
                const u16* pp = (const u16*)&par;
                float f1[4], f2[4];
#pragma unroll
                for (int e = 0; e < 4; ++e) {
                    float th = pg * inv[e];
                    float sv = __sinf(th), cv = __cosf(th);  // v_sin/v_cos, |th|<=1023
                    float x1 = bf2f(cp[e]), x2 = bf2f(pp[e]);
                    f1[e] = x1 * cv - x2 * sv;
                    f2[e] = x2 * cv + x1 * sv;
                }
                uint2 o1, o2;
                o1.x = cvtpk(f1[0], f1[1]); o1.y = cvtpk(f1[2], f1[3]);
                o2.x = cvtpk(f2[0], f2[1]); o2.y = cvtpk(f2[2], f2[3]);
                const long rowb = (hb + p0 + pos_l) * 128;
                *(uint2*)(dst + rowb + i0) = o1;
                *(uint2*)(dst + rowb + i0 + 64) = o2;
            }
        } else {
            // V: store transposed into vT[32][128][1024]
            const long vrow = ((long)(b * 16 + h)) * 128;
#pragma unroll
            for (int c = 0; c < 8; ++c) {
                const int lin2 = c * 2048 + tid * 8;
                const int dk = lin2 >> 7;
                const int ps = lin2 & 127;
                ushort4 o1, o2;
                u16* o1p = (u16*)&o1;
                u16* o2p = (u16*)&o2;
#pragma unroll
                for (int e = 0; e < 4; ++e) {
                    o1p[e] = sm.T[(ps + e) * 132 + dk];
                    o2p[e] = sm.T[(ps + 4 + e) * 132 + dk];
                }
                u16* dst = vtb + (vrow + dk) * 1024 + p0 + ps;
                *(ushort4*)dst = o1;
                *(ushort4*)(dst + 4) = o2;
            }
        }
    } else {
        float bv[4];
#pragma unroll
        for (int j = 0; j < 4; ++j) bv[j] = bias[bn * 128 + wn * 64 + j * 16 + lm];
#pragma unroll
        for (int i = 0; i < MI; ++i) {
#pragma unroll
            for (int r = 0; r < 4; ++r) {
                const int row = bm * TM + wm * (TM / 2) + i * 16 + quad * 4 + r;
#pragma unroll
                for (int j = 0; j < 4; ++j) {
                    const int col = bn * 128 + wn * 64 + j * 16 + lm;
                    out[(long)row * 2048 + col] = acc[i][j][r] + bv[j];
                }
            }
        }
    }
}

// ---------------- flash attention (causal), S^T = K*Q^T, 2-phase dbuf prefetch ---------
// Block->work mapping (fixes round-4 pairing breakage):
//   p<256: qt=s; p>=256 (same bh,s): qt=15-s. Blocks p and p+256 are co-resident on one
//   CU (512 blocks, 2/CU, all resident at t=0) -> per-CU load = (s+1)+(16-s) = 17 tiles,
//   uniform by construction. XCD locality: xcd=p&7 carries bh in {xcd*4..xcd*4+3} only ->
//   2MB K/V + 1MB Q per 4MB L2 (was: all 32 bh per XCD).
// T5 setprio; T13 defer-max; diagonal tile split; cvt_pk packing.
__global__ __launch_bounds__(256, 2) void k_flash(const u16* __restrict__ Q,
                                                  const u16* __restrict__ Kb,
                                                  const u16* __restrict__ VT,
                                                  u16* __restrict__ R) {
    __shared__ u16 Ks[2][64 * 128];  // [key 64][d 128], swizzled mask 15
    __shared__ u16 Vs[2][128 * 64];  // [d 128][key 64], swizzled mask 7
    __shared__ u16 Ps[64 * 72];      // [q 64][key 64 + 8 pad]
    const int tid = threadIdx.x;
    const int lane = tid & 63, wave = tid >> 6;
    const int lm = lane & 15, quad = lane >> 4;
    const int p = blockIdx.x;
    const int half = p >> 8, q8 = p & 255;
    const int xcd = q8 & 7, j8 = q8 >> 3;       // j8 0..31
    const int bh = xcd * 4 + (j8 >> 3);         // 4 bh per XCD
    const int s = j8 & 7;
    const int qt = half ? (15 - s) : s;
    const long qkbase = (long)bh * 1024 * 128;
    const long vtbase = (long)bh * 128 * 1024;
    const int q0 = qt * 64;

    short8 qf[4];
    {
        const u16* qrow = Q + qkbase + (long)(q0 + wave * 16 + lm) * 128 + quad * 8;
#pragma unroll
        for (int kc = 0; kc < 4; ++kc) qf[kc] = *(const short8*)(qrow + kc * 32);
    }

    f32x4 o_acc[8] = {};
    float m_i = -INFINITY, l_i = 0.f;
    const float cl2e = 0.08838834764831845f * 1.4426950408889634f;  // 1/sqrt(128)*log2(e)

    const int kr = lane >> 4;
    const int vr = lane >> 3;
    const int vcb = (lane & 7) ^ vr;

    auto stage = [&](int buf, int kt) {
#pragma unroll
        for (int it = 0; it < 4; ++it) {
            int ch = wave * 4 + it;
            int krow = ch * 4 + kr;
            int kchunk = (lane & 15) ^ (krow & 15);
            gload_lds16(Kb + qkbase + (long)(kt * 64 + krow) * 128 + kchunk * 8,
                        (char*)Ks[buf] + ch * 1024);
            int vrow = ch * 8 + vr;
            gload_lds16(VT + vtbase + (long)vrow * 1024 + kt * 64 + vcb * 8,
                        (char*)Vs[buf] + ch * 1024);
        }
    };

    stage(0, 0);
    __syncthreads();  // implicit vmcnt(0): tile 0 ready
    int cur = 0;

    for (int kt = 0; kt <= qt; ++kt) {
        if (kt < qt) stage(cur ^ 1, kt + 1);  // issue prefetch, no wait
        asm volatile("" ::: "memory");        // keep issue before compute

        f32x4 s_acc[4] = {};
        __builtin_amdgcn_s_setprio(1);
#pragma unroll
        for (int kc = 0; kc < 4; ++kc) {
#pragma unroll
            for (int mi = 0; mi < 4; ++mi) {
                int row = mi * 16 + lm;
                int pc = (kc * 4 + quad) ^ lm;
                short8 ak = *(const short8*)&Ks[cur][row * 128 + pc * 8];
                s_acc[mi] = mfma_bf16(ak, qf[kc], s_acc[mi]);
            }
        }
        __builtin_amdgcn_s_setprio(0);
        float t[4][4];
        float cmax = -INFINITY;
        if (kt < qt) {
            // bulk tile: all keys valid (kg <= kt*64+63 < qt*64 <= qg), no mask ops
#pragma unroll
            for (int mi = 0; mi < 4; ++mi)
#pragma unroll
                for (int r = 0; r < 4; ++r) {
                    float val = s_acc[mi][r] * cl2e;
                    t[mi][r] = val;
                    cmax = fmaxf(cmax, val);
                }
        } else {
            const int qg = q0 + wave * 16 + lm;
#pragma unroll
            for (int mi = 0; mi < 4; ++mi)
#pragma unroll
                for (int r = 0; r < 4; ++r) {
                    int kg = kt * 64 + mi * 16 + quad * 4 + r;
                    float val = (kg <= qg) ? s_acc[mi][r] * cl2e : -INFINITY;
                    t[mi][r] = val;
                    cmax = fmaxf(cmax, val);
                }
        }
        cmax = fmaxf(cmax, __shfl_xor(cmax, 16));
        cmax = fmaxf(cmax, __shfl_xor(cmax, 32));
        // T13 defer-max: keep old max when per-row growth <= 8 (P bounded by 2^8)
        float m_new = fmaxf(m_i, cmax);
        const bool defer = __all(cmax - m_i <= 8.f);
        if (defer) m_new = m_i;
        float csum = 0.f;
#pragma unroll
        for (int mi = 0; mi < 4; ++mi)
#pragma unroll
            for (int r = 0; r < 4; ++r) {
                float p2 = exp2f(t[mi][r] - m_new);
                t[mi][r] = p2;
                csum += p2;
            }
        csum += __shfl_xor(csum, 16);
        csum += __shfl_xor(csum, 32);
        if (!defer) {
            float alpha = exp2f(m_i - m_new);
            float aq[4];
#pragma unroll
            for (int r = 0; r < 4; ++r) aq[r] = __shfl(alpha, quad * 4 + r, 64);
#pragma unroll
            for (int nt = 0; nt < 8; ++nt)
#pragma unroll
                for (int r = 0; r < 4; ++r) o_acc[nt][r] *= aq[r];
            l_i = l_i * alpha + csum;
        } else {
            l_i += csum;
        }
        m_i = m_new;
#pragma unroll
        for (int mi = 0; mi < 4; ++mi) {
            uint2 pk2;
            pk2.x = cvtpk(t[mi][0], t[mi][1]);
            pk2.y = cvtpk(t[mi][2], t[mi][3]);
            *(uint2*)&Ps[(wave * 16 + lm) * 72 + mi * 16 + quad * 4] = pk2;
        }
        __builtin_amdgcn_s_setprio(1);
#pragma unroll
        for (int kc = 0; kc < 2; ++kc) {
            short8 ap = *(const short8*)&Ps[(wave * 16 + lm) * 72 + kc * 32 + quad * 8];
#pragma unroll
            for (int nt = 0; nt < 8; ++nt) {
                int row = nt * 16 + lm;
                int pc = (kc * 4 + quad) ^ (lm & 7);
                short8 bv = *(const short8*)&Vs[cur][row * 64 + pc * 8];
                o_acc[nt] = mfma_bf16(ap, bv, o_acc[nt]);
            }
        }
        __builtin_amdgcn_s_setprio(0);
        __syncthreads();  // implicit vmcnt(0): prefetch landed; Ps WAR fence
        cur ^= 1;
    }
    float lq[4], il[4];
#pragma unroll
    for (int r = 0; r < 4; ++r) lq[r] = __shfl(l_i, quad * 4 + r, 64);
#pragma unroll
    for (int r = 0; r < 4; ++r) il[r] = 1.0f / lq[r];
    const int b = bh >> 4, h = bh & 15;
    const int pos0 = q0 + wave * 16 + quad * 4;
#pragma unroll
    for (int nt = 0; nt < 8; ++nt) {
        const int col = h * 128 + nt * 16 + lm;
        const u32 p01 = cvtpk(o_acc[nt][0] * il[0], o_acc[nt][1] * il[1]);
        const u32 p23 = cvtpk(o_acc[nt][2] * il[2], o_acc[nt][3] * il[3]);
        R[((long)b * 1024 + pos0 + 0) * 2048 + col] = (u16)p01;
        R[((long)b * 1024 + pos0 + 1) * 2048 + col] = (u16)(p01 >> 16);
        R[((long)b * 1024 + pos0 + 2) * 2048 + col] = (u16)p23;
        R[((long)b * 1024 + pos0 + 3) * 2048 + col] = (u16)(p23 >> 16);
    }
}

extern "C" void kernel_launch(void* const* d_in, const int* in_sizes, int n_in,
                              void* d_out, int out_size, void* d_ws, size_t ws_size,
                              hipStream_t stream) {
    const float* x    = (const float*)d_in[0];
    const float* Wqkv = (const float*)d_in[2];
    const float* Wout = (const float*)d_in[3];
    const float* bout = (const float*)d_in[4];
    float* out = (float*)d_out;

    char* ws = (char*)d_ws;
    u16* x_bf  = (u16*)(ws);                 // 8MB; dead after qkv GEMM
    u16* rbuf  = x_bf;                       // reuse: written by flash
    u16* WqkvT = (u16*)(ws + (8L << 20));    // 24MB
    u16* WoutT = (u16*)(ws + (32L << 20));   // 8MB
    u16* qbuf  = (u16*)(ws + (40L << 20));   // 8MB (roped)
    u16* kbuf  = (u16*)(ws + (48L << 20));   // 8MB (roped)
    u16* vtbuf = (u16*)(ws + (56L << 20));   // 8MB, vT[32][128][1024]

    k_prep<<<8192, 256, 0, stream>>>(x, Wqkv, Wout, x_bf, WqkvT, WoutT);
    k_gemm<0, 128><<<dim3(16, 48), 256, 0, stream>>>(x_bf, WqkvT, 2048, qbuf, kbuf, vtbuf,
                                                     nullptr, nullptr);
    k_flash<<<512, 256, 0, stream>>>(qbuf, kbuf, vtbuf, rbuf);
    k_gemm<1, 64><<<dim3(32, 16), 256, 0, stream>>>(rbuf, WoutT, 2048, nullptr, nullptr,
                                                    nullptr, out, bout);
}